// Round 16
// baseline (913.229 us; speedup 1.0000x reference)
//
// CTRNN MI355X — R16: proj -> MFMA f16 (scan untouched from R15)
#include <hip/hip_runtime.h>

#define T_STEPS 1024
#define BATCH   64
#define IDIM    128
#define HDIM    512
#define ALPHA_F 0.02f
#define NLOG2E  (-1.4426950408889634f)

typedef _Float16 half2_t __attribute__((ext_vector_type(2)));
typedef _Float16 f16x8 __attribute__((ext_vector_type(8)));
typedef float f32x4 __attribute__((ext_vector_type(4)));
typedef unsigned int uint32;

__device__ __forceinline__ uint32 pk2(float a, float b) {
  auto p = __builtin_amdgcn_cvt_pkrtz(a, b);
  return __builtin_bit_cast(uint32, p);
}

__device__ __forceinline__ int dot4i8(uint32 a, uint32 b, int c) {
#if __has_builtin(__builtin_amdgcn_sdot4)
  return __builtin_amdgcn_sdot4((int)a, (int)b, c, false);
#else
  int s = c;
  s += (int)(signed char)(a)        * (int)(signed char)(b);
  s += (int)(signed char)(a >> 8)   * (int)(signed char)(b >> 8);
  s += (int)(signed char)(a >> 16)  * (int)(signed char)(b >> 16);
  s += (int)(signed char)(a >> 24)  * (int)(signed char)(b >> 24);
  return s;
#endif
}

__device__ __forceinline__ uint32 pkq(float v0, float v1, float v2, float v3, float inv) {
  int i0 = __float2int_rn(v0 * inv), i1 = __float2int_rn(v1 * inv);
  int i2 = __float2int_rn(v2 * inv), i3 = __float2int_rn(v3 * inv);
  return (uint32)(i0 & 255) | ((uint32)(i1 & 255) << 8) |
         ((uint32)(i2 & 255) << 16) | ((uint32)(i3 & 255) << 24);
}

__device__ __forceinline__ float fast_rcp(float x) {
#if __has_builtin(__builtin_amdgcn_rcpf)
  return __builtin_amdgcn_rcpf(x);
#else
  return 1.0f / x;
#endif
}

__device__ __forceinline__ int dpp_xor1(int x) {
#if __has_builtin(__builtin_amdgcn_mov_dpp)
  return __builtin_amdgcn_mov_dpp(x, 0xB1, 0xF, 0xF, true);  // quad_perm [1,0,3,2]
#else
  return __shfl_xor(x, 1);
#endif
}
__device__ __forceinline__ int dpp_xor2(int x) {
#if __has_builtin(__builtin_amdgcn_mov_dpp)
  return __builtin_amdgcn_mov_dpp(x, 0x4E, 0xF, 0xF, true);  // quad_perm [2,3,0,1]
#else
  return __shfl_xor(x, 2);
#endif
}
__device__ __forceinline__ int swz_xor4(int x) {
#if __has_builtin(__builtin_amdgcn_ds_swizzle)
  return __builtin_amdgcn_ds_swizzle(x, 0x101F);  // BitMode xor=4
#else
  return __shfl_xor(x, 4);
#endif
}
__device__ __forceinline__ float fxor1(float x) {
  return __builtin_bit_cast(float, dpp_xor1(__builtin_bit_cast(int, x)));
}
__device__ __forceinline__ float fxor2(float x) {
  return __builtin_bit_cast(float, dpp_xor2(__builtin_bit_cast(int, x)));
}
__device__ __forceinline__ float fxor4(float x) {
  return __builtin_bit_cast(float, swz_xor4(__builtin_bit_cast(int, x)));
}

// pack 8 f32 -> f16x8 fragment (RTZ, same rounding as the old dot2 path)
__device__ __forceinline__ f16x8 pk8(float4 lo, float4 hi) {
  uint4 u = make_uint4(pk2(lo.x, lo.y), pk2(lo.z, lo.w),
                       pk2(hi.x, hi.y), pk2(hi.z, hi.w));
  return __builtin_bit_cast(f16x8, u);
}

// ---------------------------------------------------------------------------
// proj via MFMA f16: xp[m][j] = NLOG2E * sum_k x[m][k] * Win[j][k]
// One 16x16 output tile per wave per m-iter; K=128 as 4 x mfma_16x16x32_f16.
// B (Win) fragments held in regs across a grid-strided m-loop; A (x) loaded
// f32 and cvt_pkrtz'd in-flight (hidden under mfma issue).
// Fragment maps (m89-verified D; standard A/B): lane l = 16*kg + r16:
//   A[m = mbase + r16][k = 32*kb + 8*kg + i]   (i = 0..7)
//   B[k = 32*kb + 8*kg + i][j = jbase + r16]   == Win[jbase+r16][k...]
//   D[m = mbase + 4*kg + q][j = jbase + r16]   (q = reg 0..3)
// ---------------------------------------------------------------------------
__global__ __launch_bounds__(256) void ctrnn_proj_mfma(
    const float* __restrict__ x,    // [rows][128]
    const float* __restrict__ Win,  // [512][128]
    float* __restrict__ xp,         // [rows][512], pre-scaled by -log2e
    int rows) {
  const int lane = threadIdx.x & 63;
  const int wv   = threadIdx.x >> 6;               // wave 0..3
  const int r16  = lane & 15;
  const int kg   = lane >> 4;                      // 0..3
  const int jbase = (blockIdx.y * 4 + wv) * 16;    // gridDim.y = 8 -> j in [0,512)

  // B fragments: Win rows jbase..jbase+15, K=128 in 4 chunks of 32
  f16x8 bf[4];
#pragma unroll
  for (int kb = 0; kb < 4; ++kb) {
    const float* wp = Win + (size_t)(jbase + r16) * IDIM + 32 * kb + 8 * kg;
    float4 lo = *(const float4*)(wp);
    float4 hi = *(const float4*)(wp + 4);
    bf[kb] = pk8(lo, hi);
  }

  const int mtiles = rows >> 4;
  for (int mt = blockIdx.x; mt < mtiles; mt += gridDim.x) {
    const int mbase = mt << 4;
    f32x4 acc = {0.f, 0.f, 0.f, 0.f};
#pragma unroll
    for (int kb = 0; kb < 4; ++kb) {
      const float* xr = x + (size_t)(mbase + r16) * IDIM + 32 * kb + 8 * kg;
      float4 lo = *(const float4*)(xr);
      float4 hi = *(const float4*)(xr + 4);
      acc = __builtin_amdgcn_mfma_f32_16x16x32_f16(pk8(lo, hi), bf[kb], acc, 0, 0, 0);
    }
    float* op = xp + (size_t)(mbase + 4 * kg) * HDIM + jbase + r16;
#pragma unroll
    for (int q = 0; q < 4; ++q)
      op[(size_t)q * HDIM] = acc[q] * NLOG2E;
  }
}

// ---------------------------------------------------------------------------
// scan kernel (UNCHANGED from R15): 1 block/batch, 512 threads (2 waves/SIMD).
// thread j: g = j&7 (col-eighth, 64 cols = 16 i8 dwords), o = j>>3 (rows
// 8o..8o+7); acc slot i holds row 8o+(i^g); 7-exchange DPP/swizzle reduce;
// own row lands in slot 0. h mirror: i8, row r at byte r+16*(r>>6).
// ---------------------------------------------------------------------------
__global__ __launch_bounds__(512)
__attribute__((amdgpu_waves_per_eu(2, 2)))
void ctrnn_scan(
    const float* __restrict__ xp,  // [ct][BATCH][HDIM], pre-scaled by -log2e
    const float* __restrict__ Wh,  // [512][512]
    const float* __restrict__ h0,  // [512]
    float* __restrict__ out,       // [T][B][H] then [B][H] final hidden
    int t0, int ct) {
  const int b = blockIdx.x;
  const int j = threadIdx.x;   // == output row n
  const int g = j & 7;
  const int o = j >> 3;

  __shared__ __attribute__((aligned(16))) unsigned char hq[2][640];

  // ---- pass 1: per-slot local absmax over 64 cols (slot i <-> row 8o+(i^g)) ----
  float m[8];
#pragma unroll
  for (int i = 0; i < 8; ++i) {
    const float4* wr = (const float4*)(Wh + (size_t)(8 * o + (i ^ g)) * HDIM + 64 * g);
    float mm = 0.f;
#pragma unroll
    for (int c = 0; c < 16; ++c) {
      float4 v = wr[c];
      mm = fmaxf(mm, fmaxf(fmaxf(fabsf(v.x), fabsf(v.y)), fmaxf(fabsf(v.z), fabsf(v.w))));
    }
    m[i] = mm;
  }
  {  // allreduce per row across the 8 lanes (slot-permuted partners)
    float t[8];
#pragma unroll
    for (int i = 0; i < 8; ++i) t[i] = fmaxf(m[i], fxor1(m[i ^ 1]));
#pragma unroll
    for (int i = 0; i < 8; ++i) m[i] = fmaxf(t[i], fxor2(t[i ^ 2]));
#pragma unroll
    for (int i = 0; i < 8; ++i) t[i] = fmaxf(m[i], fxor4(m[i ^ 4]));
#pragma unroll
    for (int i = 0; i < 8; ++i) m[i] = t[i];
  }

  // ---- pass 2: quantize 8 row-slices (16 dwords each) into w[128] ----
  uint32 w[128];
#pragma unroll
  for (int i = 0; i < 8; ++i) {
    const float rm = m[i];
    const float inv = (rm > 0.f) ? 127.f / rm : 0.f;
    const float4* wr = (const float4*)(Wh + (size_t)(8 * o + (i ^ g)) * HDIM + 64 * g);
#pragma unroll
    for (int c = 0; c < 16; ++c) {
      float4 v = wr[c];
      w[i * 16 + c] = pkq(v.x, v.y, v.z, v.w, inv);
    }
  }
  // afac = -log2e * fscale (own row == slot 0); xp already pre-scaled
  const float afac = m[0] * (1.f / (127.f * 127.f)) * NLOG2E;

  // ---- initial hidden: h (f32) in register, i8 mirror via b8 write ----
  float h;
  if (t0 == 0) h = h0[j];
  else h = out[((size_t)(t0 - 1) * BATCH + b) * HDIM + j];
  hq[0][j + 16 * (j >> 6)] = (unsigned char)(__float2int_rn(h * 127.f));
  __syncthreads();

  const float* xpp = xp + (size_t)b * HDIM + j;
  float* outp = out + ((size_t)t0 * BATCH + b) * HDIM + j;
  const size_t BH = (size_t)BATCH * HDIM;

  int cur = 0;
#pragma unroll 2
  for (int t = 0; t < ct; ++t) {
    const float xpw = *xpp;  // pre-scaled; L2 latency hides under dots

    const uint4* hb = (const uint4*)(&hq[cur][80 * g]);
    int a0 = 0, a1 = 0, a2 = 0, a3 = 0, a4 = 0, a5 = 0, a6 = 0, a7 = 0;
#pragma unroll
    for (int c = 0; c < 4; ++c) {
      const uint4 hv = hb[c];  // direct static index: no select chain
      a0 = dot4i8(w[0 * 16 + 4 * c + 0], hv.x, a0);
      a0 = dot4i8(w[0 * 16 + 4 * c + 1], hv.y, a0);
      a0 = dot4i8(w[0 * 16 + 4 * c + 2], hv.z, a0);
      a0 = dot4i8(w[0 * 16 + 4 * c + 3], hv.w, a0);
      a1 = dot4i8(w[1 * 16 + 4 * c + 0], hv.x, a1);
      a1 = dot4i8(w[1 * 16 + 4 * c + 1], hv.y, a1);
      a1 = dot4i8(w[1 * 16 + 4 * c + 2], hv.z, a1);
      a1 = dot4i8(w[1 * 16 + 4 * c + 3], hv.w, a1);
      a2 = dot4i8(w[2 * 16 + 4 * c + 0], hv.x, a2);
      a2 = dot4i8(w[2 * 16 + 4 * c + 1], hv.y, a2);
      a2 = dot4i8(w[2 * 16 + 4 * c + 2], hv.z, a2);
      a2 = dot4i8(w[2 * 16 + 4 * c + 3], hv.w, a2);
      a3 = dot4i8(w[3 * 16 + 4 * c + 0], hv.x, a3);
      a3 = dot4i8(w[3 * 16 + 4 * c + 1], hv.y, a3);
      a3 = dot4i8(w[3 * 16 + 4 * c + 2], hv.z, a3);
      a3 = dot4i8(w[3 * 16 + 4 * c + 3], hv.w, a3);
      a4 = dot4i8(w[4 * 16 + 4 * c + 0], hv.x, a4);
      a4 = dot4i8(w[4 * 16 + 4 * c + 1], hv.y, a4);
      a4 = dot4i8(w[4 * 16 + 4 * c + 2], hv.z, a4);
      a4 = dot4i8(w[4 * 16 + 4 * c + 3], hv.w, a4);
      a5 = dot4i8(w[5 * 16 + 4 * c + 0], hv.x, a5);
      a5 = dot4i8(w[5 * 16 + 4 * c + 1], hv.y, a5);
      a5 = dot4i8(w[5 * 16 + 4 * c + 2], hv.z, a5);
      a5 = dot4i8(w[5 * 16 + 4 * c + 3], hv.w, a5);
      a6 = dot4i8(w[6 * 16 + 4 * c + 0], hv.x, a6);
      a6 = dot4i8(w[6 * 16 + 4 * c + 1], hv.y, a6);
      a6 = dot4i8(w[6 * 16 + 4 * c + 2], hv.z, a6);
      a6 = dot4i8(w[6 * 16 + 4 * c + 3], hv.w, a6);
      a7 = dot4i8(w[7 * 16 + 4 * c + 0], hv.x, a7);
      a7 = dot4i8(w[7 * 16 + 4 * c + 1], hv.y, a7);
      a7 = dot4i8(w[7 * 16 + 4 * c + 2], hv.z, a7);
      a7 = dot4i8(w[7 * 16 + 4 * c + 3], hv.w, a7);
    }
    // 7-exchange tree (own row ends in slot 0)
    const int q0 = a0 + dpp_xor1(a1);
    const int q1 = a2 + dpp_xor1(a3);
    const int q2 = a4 + dpp_xor1(a5);
    const int q3 = a6 + dpp_xor1(a7);
    const int r0 = q0 + dpp_xor2(q1);
    const int r1 = q2 + dpp_xor2(q3);
    const int res = r0 + swz_xor4(r1);

    // sigmoid via exp2 + single-inst rcp: e = 2^(afac*res + xpw) == e^{-z}
    const float e = exp2f((float)res * afac + xpw);
    const float s = fast_rcp(1.0f + e);
    h = h * (1.0f - ALPHA_F) + s * ALPHA_F;

    // i8 mirror write (single byte) BEFORE barrier
    hq[cur ^ 1][j + 16 * (j >> 6)] = (unsigned char)(__float2int_rn(h * 127.f));
    __syncthreads();

    *outp = h;  // after barrier: issues in the shadow of next step's dots
    cur ^= 1;
    xpp += BH;
    outp += BH;
  }

  if (t0 + ct == T_STEPS) {
    out[(size_t)T_STEPS * BATCH * HDIM + (size_t)b * HDIM + j] = h;
  }
}

// ---------------------------------------------------------------------------
extern "C" void kernel_launch(void* const* d_in, const int* in_sizes, int n_in,
                              void* d_out, int out_size, void* d_ws, size_t ws_size,
                              hipStream_t stream) {
  const float* x   = (const float*)d_in[0];
  const float* Win = (const float*)d_in[1];
  const float* Wh  = (const float*)d_in[2];
  const float* h0  = (const float*)d_in[3];
  float* out = (float*)d_out;
  float* xp  = (float*)d_ws;

  const size_t step_bytes = (size_t)BATCH * HDIM * sizeof(float);  // 128 KB
  int ct_max = (int)(ws_size / step_bytes);
  if (ct_max < 1) ct_max = 1;
  if (ct_max > T_STEPS) ct_max = T_STEPS;

  for (int t0 = 0; t0 < T_STEPS; t0 += ct_max) {
    const int ct = (T_STEPS - t0 < ct_max) ? (T_STEPS - t0) : ct_max;
    const int rows = ct * BATCH;
    const int mtiles = rows >> 4;
    const int gx = (mtiles < 256) ? mtiles : 256;
    hipLaunchKernelGGL(ctrnn_proj_mfma, dim3(gx, 8), dim3(256), 0, stream,
                       x + (size_t)t0 * BATCH * IDIM, Win, xp, rows);
    hipLaunchKernelGGL(ctrnn_scan, dim3(BATCH), dim3(512), 0, stream,
                       xp, Wh, h0, out, t0, ct);
  }
}

// Round 17
// 858.993 us; speedup vs baseline: 1.0631x; 1.0631x over previous
//
// CTRNN MI355X — R17: MFMA proj with 4x j-tile A-reuse (16 mfma per A-load); scan = R15
#include <hip/hip_runtime.h>

#define T_STEPS 1024
#define BATCH   64
#define IDIM    128
#define HDIM    512
#define ALPHA_F 0.02f
#define NLOG2E  (-1.4426950408889634f)

typedef _Float16 half2_t __attribute__((ext_vector_type(2)));
typedef _Float16 f16x8 __attribute__((ext_vector_type(8)));
typedef float f32x4 __attribute__((ext_vector_type(4)));
typedef unsigned int uint32;

__device__ __forceinline__ uint32 pk2(float a, float b) {
  auto p = __builtin_amdgcn_cvt_pkrtz(a, b);
  return __builtin_bit_cast(uint32, p);
}

__device__ __forceinline__ int dot4i8(uint32 a, uint32 b, int c) {
#if __has_builtin(__builtin_amdgcn_sdot4)
  return __builtin_amdgcn_sdot4((int)a, (int)b, c, false);
#else
  int s = c;
  s += (int)(signed char)(a)        * (int)(signed char)(b);
  s += (int)(signed char)(a >> 8)   * (int)(signed char)(b >> 8);
  s += (int)(signed char)(a >> 16)  * (int)(signed char)(b >> 16);
  s += (int)(signed char)(a >> 24)  * (int)(signed char)(b >> 24);
  return s;
#endif
}

__device__ __forceinline__ uint32 pkq(float v0, float v1, float v2, float v3, float inv) {
  int i0 = __float2int_rn(v0 * inv), i1 = __float2int_rn(v1 * inv);
  int i2 = __float2int_rn(v2 * inv), i3 = __float2int_rn(v3 * inv);
  return (uint32)(i0 & 255) | ((uint32)(i1 & 255) << 8) |
         ((uint32)(i2 & 255) << 16) | ((uint32)(i3 & 255) << 24);
}

__device__ __forceinline__ float fast_rcp(float x) {
#if __has_builtin(__builtin_amdgcn_rcpf)
  return __builtin_amdgcn_rcpf(x);
#else
  return 1.0f / x;
#endif
}

__device__ __forceinline__ int dpp_xor1(int x) {
#if __has_builtin(__builtin_amdgcn_mov_dpp)
  return __builtin_amdgcn_mov_dpp(x, 0xB1, 0xF, 0xF, true);  // quad_perm [1,0,3,2]
#else
  return __shfl_xor(x, 1);
#endif
}
__device__ __forceinline__ int dpp_xor2(int x) {
#if __has_builtin(__builtin_amdgcn_mov_dpp)
  return __builtin_amdgcn_mov_dpp(x, 0x4E, 0xF, 0xF, true);  // quad_perm [2,3,0,1]
#else
  return __shfl_xor(x, 2);
#endif
}
__device__ __forceinline__ int swz_xor4(int x) {
#if __has_builtin(__builtin_amdgcn_ds_swizzle)
  return __builtin_amdgcn_ds_swizzle(x, 0x101F);  // BitMode xor=4
#else
  return __shfl_xor(x, 4);
#endif
}
__device__ __forceinline__ float fxor1(float x) {
  return __builtin_bit_cast(float, dpp_xor1(__builtin_bit_cast(int, x)));
}
__device__ __forceinline__ float fxor2(float x) {
  return __builtin_bit_cast(float, dpp_xor2(__builtin_bit_cast(int, x)));
}
__device__ __forceinline__ float fxor4(float x) {
  return __builtin_bit_cast(float, swz_xor4(__builtin_bit_cast(int, x)));
}

// pack 8 f32 -> f16x8 fragment (RTZ, same rounding as the old dot2 path)
__device__ __forceinline__ f16x8 pk8(float4 lo, float4 hi) {
  uint4 u = make_uint4(pk2(lo.x, lo.y), pk2(lo.z, lo.w),
                       pk2(hi.x, hi.y), pk2(hi.z, hi.w));
  return __builtin_bit_cast(f16x8, u);
}

// ---------------------------------------------------------------------------
// proj via MFMA f16 with A-reuse: xp[m][j] = NLOG2E * sum_k x[m][k]*Win[j][k].
// Each wave owns FOUR 16-col j-tiles (64 cols): B frags bf[4][4] loaded once
// (64 VGPRs); per m-iter ONE A-tile load (16 dwordx4 + 16 cvt) feeds 16 MFMAs
// (4 j-tiles x 4 k-blocks). gridDim.y = 2 -> x re-read only 2x.
// Fragment maps (m89-verified D; lane l = 16*kg + r16):
//   A[mbase + r16][32*kb + 8*kg + i],  B[32*kb + 8*kg + i][jt-col r16],
//   D[mbase + 4*kg + q][jt-col r16].
// ---------------------------------------------------------------------------
__global__ __launch_bounds__(256) void ctrnn_proj_mfma(
    const float* __restrict__ x,    // [rows][128]
    const float* __restrict__ Win,  // [512][128]
    float* __restrict__ xp,         // [rows][512], pre-scaled by -log2e
    int rows) {
  const int lane = threadIdx.x & 63;
  const int wv   = threadIdx.x >> 6;                 // wave 0..3
  const int r16  = lane & 15;
  const int kg   = lane >> 4;                        // 0..3
  const int jbase = blockIdx.y * 256 + wv * 64;      // wave's 64-col span

  // B fragments: 4 j-tiles x 4 k-blocks (Win rows jbase+16*jt+r16)
  f16x8 bf[4][4];
#pragma unroll
  for (int jt = 0; jt < 4; ++jt) {
#pragma unroll
    for (int kb = 0; kb < 4; ++kb) {
      const float* wp = Win + (size_t)(jbase + 16 * jt + r16) * IDIM + 32 * kb + 8 * kg;
      float4 lo = *(const float4*)(wp);
      float4 hi = *(const float4*)(wp + 4);
      bf[jt][kb] = pk8(lo, hi);
    }
  }

  const int mtiles = rows >> 4;
  for (int mt = blockIdx.x; mt < mtiles; mt += gridDim.x) {
    const int mbase = mt << 4;
    // one A-tile load per m-iter, reused across 4 j-tiles
    f16x8 af[4];
#pragma unroll
    for (int kb = 0; kb < 4; ++kb) {
      const float* xr = x + (size_t)(mbase + r16) * IDIM + 32 * kb + 8 * kg;
      float4 lo = *(const float4*)(xr);
      float4 hi = *(const float4*)(xr + 4);
      af[kb] = pk8(lo, hi);
    }
    f32x4 acc0 = {0.f, 0.f, 0.f, 0.f};
    f32x4 acc1 = {0.f, 0.f, 0.f, 0.f};
    f32x4 acc2 = {0.f, 0.f, 0.f, 0.f};
    f32x4 acc3 = {0.f, 0.f, 0.f, 0.f};
#pragma unroll
    for (int kb = 0; kb < 4; ++kb) {
      acc0 = __builtin_amdgcn_mfma_f32_16x16x32_f16(af[kb], bf[0][kb], acc0, 0, 0, 0);
      acc1 = __builtin_amdgcn_mfma_f32_16x16x32_f16(af[kb], bf[1][kb], acc1, 0, 0, 0);
      acc2 = __builtin_amdgcn_mfma_f32_16x16x32_f16(af[kb], bf[2][kb], acc2, 0, 0, 0);
      acc3 = __builtin_amdgcn_mfma_f32_16x16x32_f16(af[kb], bf[3][kb], acc3, 0, 0, 0);
    }
    float* op = xp + (size_t)(mbase + 4 * kg) * HDIM + jbase + r16;
#pragma unroll
    for (int q = 0; q < 4; ++q) {
      float* row = op + (size_t)q * HDIM;
      row[0]  = acc0[q] * NLOG2E;
      row[16] = acc1[q] * NLOG2E;
      row[32] = acc2[q] * NLOG2E;
      row[48] = acc3[q] * NLOG2E;
    }
  }
}

// ---------------------------------------------------------------------------
// scan kernel (UNCHANGED from R15): 1 block/batch, 512 threads (2 waves/SIMD).
// thread j: g = j&7 (col-eighth, 64 cols = 16 i8 dwords), o = j>>3 (rows
// 8o..8o+7); acc slot i holds row 8o+(i^g); 7-exchange DPP/swizzle reduce;
// own row lands in slot 0. h mirror: i8, row r at byte r+16*(r>>6).
// ---------------------------------------------------------------------------
__global__ __launch_bounds__(512)
__attribute__((amdgpu_waves_per_eu(2, 2)))
void ctrnn_scan(
    const float* __restrict__ xp,  // [ct][BATCH][HDIM], pre-scaled by -log2e
    const float* __restrict__ Wh,  // [512][512]
    const float* __restrict__ h0,  // [512]
    float* __restrict__ out,       // [T][B][H] then [B][H] final hidden
    int t0, int ct) {
  const int b = blockIdx.x;
  const int j = threadIdx.x;   // == output row n
  const int g = j & 7;
  const int o = j >> 3;

  __shared__ __attribute__((aligned(16))) unsigned char hq[2][640];

  // ---- pass 1: per-slot local absmax over 64 cols (slot i <-> row 8o+(i^g)) ----
  float m[8];
#pragma unroll
  for (int i = 0; i < 8; ++i) {
    const float4* wr = (const float4*)(Wh + (size_t)(8 * o + (i ^ g)) * HDIM + 64 * g);
    float mm = 0.f;
#pragma unroll
    for (int c = 0; c < 16; ++c) {
      float4 v = wr[c];
      mm = fmaxf(mm, fmaxf(fmaxf(fabsf(v.x), fabsf(v.y)), fmaxf(fabsf(v.z), fabsf(v.w))));
    }
    m[i] = mm;
  }
  {  // allreduce per row across the 8 lanes (slot-permuted partners)
    float t[8];
#pragma unroll
    for (int i = 0; i < 8; ++i) t[i] = fmaxf(m[i], fxor1(m[i ^ 1]));
#pragma unroll
    for (int i = 0; i < 8; ++i) m[i] = fmaxf(t[i], fxor2(t[i ^ 2]));
#pragma unroll
    for (int i = 0; i < 8; ++i) t[i] = fmaxf(m[i], fxor4(m[i ^ 4]));
#pragma unroll
    for (int i = 0; i < 8; ++i) m[i] = t[i];
  }

  // ---- pass 2: quantize 8 row-slices (16 dwords each) into w[128] ----
  uint32 w[128];
#pragma unroll
  for (int i = 0; i < 8; ++i) {
    const float rm = m[i];
    const float inv = (rm > 0.f) ? 127.f / rm : 0.f;
    const float4* wr = (const float4*)(Wh + (size_t)(8 * o + (i ^ g)) * HDIM + 64 * g);
#pragma unroll
    for (int c = 0; c < 16; ++c) {
      float4 v = wr[c];
      w[i * 16 + c] = pkq(v.x, v.y, v.z, v.w, inv);
    }
  }
  // afac = -log2e * fscale (own row == slot 0); xp already pre-scaled
  const float afac = m[0] * (1.f / (127.f * 127.f)) * NLOG2E;

  // ---- initial hidden: h (f32) in register, i8 mirror via b8 write ----
  float h;
  if (t0 == 0) h = h0[j];
  else h = out[((size_t)(t0 - 1) * BATCH + b) * HDIM + j];
  hq[0][j + 16 * (j >> 6)] = (unsigned char)(__float2int_rn(h * 127.f));
  __syncthreads();

  const float* xpp = xp + (size_t)b * HDIM + j;
  float* outp = out + ((size_t)t0 * BATCH + b) * HDIM + j;
  const size_t BH = (size_t)BATCH * HDIM;

  int cur = 0;
#pragma unroll 2
  for (int t = 0; t < ct; ++t) {
    const float xpw = *xpp;  // pre-scaled; L2 latency hides under dots

    const uint4* hb = (const uint4*)(&hq[cur][80 * g]);
    int a0 = 0, a1 = 0, a2 = 0, a3 = 0, a4 = 0, a5 = 0, a6 = 0, a7 = 0;
#pragma unroll
    for (int c = 0; c < 4; ++c) {
      const uint4 hv = hb[c];  // direct static index: no select chain
      a0 = dot4i8(w[0 * 16 + 4 * c + 0], hv.x, a0);
      a0 = dot4i8(w[0 * 16 + 4 * c + 1], hv.y, a0);
      a0 = dot4i8(w[0 * 16 + 4 * c + 2], hv.z, a0);
      a0 = dot4i8(w[0 * 16 + 4 * c + 3], hv.w, a0);
      a1 = dot4i8(w[1 * 16 + 4 * c + 0], hv.x, a1);
      a1 = dot4i8(w[1 * 16 + 4 * c + 1], hv.y, a1);
      a1 = dot4i8(w[1 * 16 + 4 * c + 2], hv.z, a1);
      a1 = dot4i8(w[1 * 16 + 4 * c + 3], hv.w, a1);
      a2 = dot4i8(w[2 * 16 + 4 * c + 0], hv.x, a2);
      a2 = dot4i8(w[2 * 16 + 4 * c + 1], hv.y, a2);
      a2 = dot4i8(w[2 * 16 + 4 * c + 2], hv.z, a2);
      a2 = dot4i8(w[2 * 16 + 4 * c + 3], hv.w, a2);
      a3 = dot4i8(w[3 * 16 + 4 * c + 0], hv.x, a3);
      a3 = dot4i8(w[3 * 16 + 4 * c + 1], hv.y, a3);
      a3 = dot4i8(w[3 * 16 + 4 * c + 2], hv.z, a3);
      a3 = dot4i8(w[3 * 16 + 4 * c + 3], hv.w, a3);
      a4 = dot4i8(w[4 * 16 + 4 * c + 0], hv.x, a4);
      a4 = dot4i8(w[4 * 16 + 4 * c + 1], hv.y, a4);
      a4 = dot4i8(w[4 * 16 + 4 * c + 2], hv.z, a4);
      a4 = dot4i8(w[4 * 16 + 4 * c + 3], hv.w, a4);
      a5 = dot4i8(w[5 * 16 + 4 * c + 0], hv.x, a5);
      a5 = dot4i8(w[5 * 16 + 4 * c + 1], hv.y, a5);
      a5 = dot4i8(w[5 * 16 + 4 * c + 2], hv.z, a5);
      a5 = dot4i8(w[5 * 16 + 4 * c + 3], hv.w, a5);
      a6 = dot4i8(w[6 * 16 + 4 * c + 0], hv.x, a6);
      a6 = dot4i8(w[6 * 16 + 4 * c + 1], hv.y, a6);
      a6 = dot4i8(w[6 * 16 + 4 * c + 2], hv.z, a6);
      a6 = dot4i8(w[6 * 16 + 4 * c + 3], hv.w, a6);
      a7 = dot4i8(w[7 * 16 + 4 * c + 0], hv.x, a7);
      a7 = dot4i8(w[7 * 16 + 4 * c + 1], hv.y, a7);
      a7 = dot4i8(w[7 * 16 + 4 * c + 2], hv.z, a7);
      a7 = dot4i8(w[7 * 16 + 4 * c + 3], hv.w, a7);
    }
    // 7-exchange tree (own row ends in slot 0)
    const int q0 = a0 + dpp_xor1(a1);
    const int q1 = a2 + dpp_xor1(a3);
    const int q2 = a4 + dpp_xor1(a5);
    const int q3 = a6 + dpp_xor1(a7);
    const int r0 = q0 + dpp_xor2(q1);
    const int r1 = q2 + dpp_xor2(q3);
    const int res = r0 + swz_xor4(r1);

    // sigmoid via exp2 + single-inst rcp: e = 2^(afac*res + xpw) == e^{-z}
    const float e = exp2f((float)res * afac + xpw);
    const float s = fast_rcp(1.0f + e);
    h = h * (1.0f - ALPHA_F) + s * ALPHA_F;

    // i8 mirror write (single byte) BEFORE barrier
    hq[cur ^ 1][j + 16 * (j >> 6)] = (unsigned char)(__float2int_rn(h * 127.f));
    __syncthreads();

    *outp = h;  // after barrier: issues in the shadow of next step's dots
    cur ^= 1;
    xpp += BH;
    outp += BH;
  }

  if (t0 + ct == T_STEPS) {
    out[(size_t)T_STEPS * BATCH * HDIM + (size_t)b * HDIM + j] = h;
  }
}

// ---------------------------------------------------------------------------
extern "C" void kernel_launch(void* const* d_in, const int* in_sizes, int n_in,
                              void* d_out, int out_size, void* d_ws, size_t ws_size,
                              hipStream_t stream) {
  const float* x   = (const float*)d_in[0];
  const float* Win = (const float*)d_in[1];
  const float* Wh  = (const float*)d_in[2];
  const float* h0  = (const float*)d_in[3];
  float* out = (float*)d_out;
  float* xp  = (float*)d_ws;

  const size_t step_bytes = (size_t)BATCH * HDIM * sizeof(float);  // 128 KB
  int ct_max = (int)(ws_size / step_bytes);
  if (ct_max < 1) ct_max = 1;
  if (ct_max > T_STEPS) ct_max = T_STEPS;

  for (int t0 = 0; t0 < T_STEPS; t0 += ct_max) {
    const int ct = (T_STEPS - t0 < ct_max) ? (T_STEPS - t0) : ct_max;
    const int rows = ct * BATCH;
    const int mtiles = rows >> 4;
    const int gx = (mtiles < 1024) ? mtiles : 1024;
    hipLaunchKernelGGL(ctrnn_proj_mfma, dim3(gx, 2), dim3(256), 0, stream,
                       x + (size_t)t0 * BATCH * IDIM, Win, xp, rows);
    hipLaunchKernelGGL(ctrnn_scan, dim3(BATCH), dim3(512), 0, stream,
                       xp, Wh, h0, out, t0, ct);
  }
}

// Round 18
// 858.085 us; speedup vs baseline: 1.0643x; 1.0011x over previous
//
// CTRNN MI355X — R18: proj operand-swap (D=Win×x -> float4 stores, NLOG2E folded); scan = R15
#include <hip/hip_runtime.h>

#define T_STEPS 1024
#define BATCH   64
#define IDIM    128
#define HDIM    512
#define ALPHA_F 0.02f
#define NLOG2E  (-1.4426950408889634f)

typedef _Float16 half2_t __attribute__((ext_vector_type(2)));
typedef _Float16 f16x8 __attribute__((ext_vector_type(8)));
typedef float f32x4 __attribute__((ext_vector_type(4)));
typedef unsigned int uint32;

__device__ __forceinline__ uint32 pk2(float a, float b) {
  auto p = __builtin_amdgcn_cvt_pkrtz(a, b);
  return __builtin_bit_cast(uint32, p);
}

__device__ __forceinline__ int dot4i8(uint32 a, uint32 b, int c) {
#if __has_builtin(__builtin_amdgcn_sdot4)
  return __builtin_amdgcn_sdot4((int)a, (int)b, c, false);
#else
  int s = c;
  s += (int)(signed char)(a)        * (int)(signed char)(b);
  s += (int)(signed char)(a >> 8)   * (int)(signed char)(b >> 8);
  s += (int)(signed char)(a >> 16)  * (int)(signed char)(b >> 16);
  s += (int)(signed char)(a >> 24)  * (int)(signed char)(b >> 24);
  return s;
#endif
}

__device__ __forceinline__ uint32 pkq(float v0, float v1, float v2, float v3, float inv) {
  int i0 = __float2int_rn(v0 * inv), i1 = __float2int_rn(v1 * inv);
  int i2 = __float2int_rn(v2 * inv), i3 = __float2int_rn(v3 * inv);
  return (uint32)(i0 & 255) | ((uint32)(i1 & 255) << 8) |
         ((uint32)(i2 & 255) << 16) | ((uint32)(i3 & 255) << 24);
}

__device__ __forceinline__ float fast_rcp(float x) {
#if __has_builtin(__builtin_amdgcn_rcpf)
  return __builtin_amdgcn_rcpf(x);
#else
  return 1.0f / x;
#endif
}

__device__ __forceinline__ int dpp_xor1(int x) {
#if __has_builtin(__builtin_amdgcn_mov_dpp)
  return __builtin_amdgcn_mov_dpp(x, 0xB1, 0xF, 0xF, true);  // quad_perm [1,0,3,2]
#else
  return __shfl_xor(x, 1);
#endif
}
__device__ __forceinline__ int dpp_xor2(int x) {
#if __has_builtin(__builtin_amdgcn_mov_dpp)
  return __builtin_amdgcn_mov_dpp(x, 0x4E, 0xF, 0xF, true);  // quad_perm [2,3,0,1]
#else
  return __shfl_xor(x, 2);
#endif
}
__device__ __forceinline__ int swz_xor4(int x) {
#if __has_builtin(__builtin_amdgcn_ds_swizzle)
  return __builtin_amdgcn_ds_swizzle(x, 0x101F);  // BitMode xor=4
#else
  return __shfl_xor(x, 4);
#endif
}
__device__ __forceinline__ float fxor1(float x) {
  return __builtin_bit_cast(float, dpp_xor1(__builtin_bit_cast(int, x)));
}
__device__ __forceinline__ float fxor2(float x) {
  return __builtin_bit_cast(float, dpp_xor2(__builtin_bit_cast(int, x)));
}
__device__ __forceinline__ float fxor4(float x) {
  return __builtin_bit_cast(float, swz_xor4(__builtin_bit_cast(int, x)));
}

// pack 8 f32 -> f16x8 fragment (RTZ)
__device__ __forceinline__ f16x8 pk8(float4 lo, float4 hi) {
  uint4 u = make_uint4(pk2(lo.x, lo.y), pk2(lo.z, lo.w),
                       pk2(hi.x, hi.y), pk2(hi.z, hi.w));
  return __builtin_bit_cast(f16x8, u);
}

// ---------------------------------------------------------------------------
// proj via MFMA f16, operand-swapped: D = Win_tile x x_tile.
// A = Win fragment (rows j by lane&15), B = x fragment (cols m by lane&15) —
// same fragment DATA as R17, only the intrinsic operand order changes.
// D[j_local = 4*(lane>>4)+q][m_local = lane&15] -> each lane stores 4
// CONSECUTIVE j for one m row: one float4 store per j-tile (was 16 scalar).
// NLOG2E folded into the Win fragments at load (saves 16 v_mul per m-iter).
// ---------------------------------------------------------------------------
__global__ __launch_bounds__(256) void ctrnn_proj_mfma(
    const float* __restrict__ x,    // [rows][128]
    const float* __restrict__ Win,  // [512][128]
    float* __restrict__ xp,         // [rows][512], pre-scaled by -log2e
    int rows) {
  const int lane = threadIdx.x & 63;
  const int wv   = threadIdx.x >> 6;                 // wave 0..3
  const int r16  = lane & 15;
  const int kg   = lane >> 4;                        // 0..3
  const int jbase = blockIdx.y * 256 + wv * 64;      // wave's 64-col span

  // A fragments (Win, NLOG2E-folded): 4 j-tiles x 4 k-blocks
  f16x8 bf[4][4];
#pragma unroll
  for (int jt = 0; jt < 4; ++jt) {
#pragma unroll
    for (int kb = 0; kb < 4; ++kb) {
      const float* wp = Win + (size_t)(jbase + 16 * jt + r16) * IDIM + 32 * kb + 8 * kg;
      float4 lo = *(const float4*)(wp);
      float4 hi = *(const float4*)(wp + 4);
      lo.x *= NLOG2E; lo.y *= NLOG2E; lo.z *= NLOG2E; lo.w *= NLOG2E;
      hi.x *= NLOG2E; hi.y *= NLOG2E; hi.z *= NLOG2E; hi.w *= NLOG2E;
      bf[jt][kb] = pk8(lo, hi);
    }
  }

  const int mtiles = rows >> 4;
  for (int mt = blockIdx.x; mt < mtiles; mt += gridDim.x) {
    const int mbase = mt << 4;
    // one x-tile load per m-iter, reused across 4 j-tiles
    f16x8 af[4];
#pragma unroll
    for (int kb = 0; kb < 4; ++kb) {
      const float* xr = x + (size_t)(mbase + r16) * IDIM + 32 * kb + 8 * kg;
      float4 lo = *(const float4*)(xr);
      float4 hi = *(const float4*)(xr + 4);
      af[kb] = pk8(lo, hi);
    }
    f32x4 acc0 = {0.f, 0.f, 0.f, 0.f};
    f32x4 acc1 = {0.f, 0.f, 0.f, 0.f};
    f32x4 acc2 = {0.f, 0.f, 0.f, 0.f};
    f32x4 acc3 = {0.f, 0.f, 0.f, 0.f};
#pragma unroll
    for (int kb = 0; kb < 4; ++kb) {
      acc0 = __builtin_amdgcn_mfma_f32_16x16x32_f16(bf[0][kb], af[kb], acc0, 0, 0, 0);
      acc1 = __builtin_amdgcn_mfma_f32_16x16x32_f16(bf[1][kb], af[kb], acc1, 0, 0, 0);
      acc2 = __builtin_amdgcn_mfma_f32_16x16x32_f16(bf[2][kb], af[kb], acc2, 0, 0, 0);
      acc3 = __builtin_amdgcn_mfma_f32_16x16x32_f16(bf[3][kb], af[kb], acc3, 0, 0, 0);
    }
    // lane stores 4 consecutive j at row (mbase+r16): float4 per j-tile
    float* row = xp + (size_t)(mbase + r16) * HDIM + jbase + 4 * kg;
    *(float4*)(row)      = *(float4*)&acc0;
    *(float4*)(row + 16) = *(float4*)&acc1;
    *(float4*)(row + 32) = *(float4*)&acc2;
    *(float4*)(row + 48) = *(float4*)&acc3;
  }
}

// ---------------------------------------------------------------------------
// scan kernel (UNCHANGED from R15): 1 block/batch, 512 threads (2 waves/SIMD).
// thread j: g = j&7 (col-eighth, 64 cols = 16 i8 dwords), o = j>>3 (rows
// 8o..8o+7); acc slot i holds row 8o+(i^g); 7-exchange DPP/swizzle reduce;
// own row lands in slot 0. h mirror: i8, row r at byte r+16*(r>>6).
// ---------------------------------------------------------------------------
__global__ __launch_bounds__(512)
__attribute__((amdgpu_waves_per_eu(2, 2)))
void ctrnn_scan(
    const float* __restrict__ xp,  // [ct][BATCH][HDIM], pre-scaled by -log2e
    const float* __restrict__ Wh,  // [512][512]
    const float* __restrict__ h0,  // [512]
    float* __restrict__ out,       // [T][B][H] then [B][H] final hidden
    int t0, int ct) {
  const int b = blockIdx.x;
  const int j = threadIdx.x;   // == output row n
  const int g = j & 7;
  const int o = j >> 3;

  __shared__ __attribute__((aligned(16))) unsigned char hq[2][640];

  // ---- pass 1: per-slot local absmax over 64 cols (slot i <-> row 8o+(i^g)) ----
  float m[8];
#pragma unroll
  for (int i = 0; i < 8; ++i) {
    const float4* wr = (const float4*)(Wh + (size_t)(8 * o + (i ^ g)) * HDIM + 64 * g);
    float mm = 0.f;
#pragma unroll
    for (int c = 0; c < 16; ++c) {
      float4 v = wr[c];
      mm = fmaxf(mm, fmaxf(fmaxf(fabsf(v.x), fabsf(v.y)), fmaxf(fabsf(v.z), fabsf(v.w))));
    }
    m[i] = mm;
  }
  {  // allreduce per row across the 8 lanes (slot-permuted partners)
    float t[8];
#pragma unroll
    for (int i = 0; i < 8; ++i) t[i] = fmaxf(m[i], fxor1(m[i ^ 1]));
#pragma unroll
    for (int i = 0; i < 8; ++i) m[i] = fmaxf(t[i], fxor2(t[i ^ 2]));
#pragma unroll
    for (int i = 0; i < 8; ++i) t[i] = fmaxf(m[i], fxor4(m[i ^ 4]));
#pragma unroll
    for (int i = 0; i < 8; ++i) m[i] = t[i];
  }

  // ---- pass 2: quantize 8 row-slices (16 dwords each) into w[128] ----
  uint32 w[128];
#pragma unroll
  for (int i = 0; i < 8; ++i) {
    const float rm = m[i];
    const float inv = (rm > 0.f) ? 127.f / rm : 0.f;
    const float4* wr = (const float4*)(Wh + (size_t)(8 * o + (i ^ g)) * HDIM + 64 * g);
#pragma unroll
    for (int c = 0; c < 16; ++c) {
      float4 v = wr[c];
      w[i * 16 + c] = pkq(v.x, v.y, v.z, v.w, inv);
    }
  }
  // afac = -log2e * fscale (own row == slot 0); xp already pre-scaled
  const float afac = m[0] * (1.f / (127.f * 127.f)) * NLOG2E;

  // ---- initial hidden: h (f32) in register, i8 mirror via b8 write ----
  float h;
  if (t0 == 0) h = h0[j];
  else h = out[((size_t)(t0 - 1) * BATCH + b) * HDIM + j];
  hq[0][j + 16 * (j >> 6)] = (unsigned char)(__float2int_rn(h * 127.f));
  __syncthreads();

  const float* xpp = xp + (size_t)b * HDIM + j;
  float* outp = out + ((size_t)t0 * BATCH + b) * HDIM + j;
  const size_t BH = (size_t)BATCH * HDIM;

  int cur = 0;
#pragma unroll 2
  for (int t = 0; t < ct; ++t) {
    const float xpw = *xpp;  // pre-scaled; L2 latency hides under dots

    const uint4* hb = (const uint4*)(&hq[cur][80 * g]);
    int a0 = 0, a1 = 0, a2 = 0, a3 = 0, a4 = 0, a5 = 0, a6 = 0, a7 = 0;
#pragma unroll
    for (int c = 0; c < 4; ++c) {
      const uint4 hv = hb[c];  // direct static index: no select chain
      a0 = dot4i8(w[0 * 16 + 4 * c + 0], hv.x, a0);
      a0 = dot4i8(w[0 * 16 + 4 * c + 1], hv.y, a0);
      a0 = dot4i8(w[0 * 16 + 4 * c + 2], hv.z, a0);
      a0 = dot4i8(w[0 * 16 + 4 * c + 3], hv.w, a0);
      a1 = dot4i8(w[1 * 16 + 4 * c + 0], hv.x, a1);
      a1 = dot4i8(w[1 * 16 + 4 * c + 1], hv.y, a1);
      a1 = dot4i8(w[1 * 16 + 4 * c + 2], hv.z, a1);
      a1 = dot4i8(w[1 * 16 + 4 * c + 3], hv.w, a1);
      a2 = dot4i8(w[2 * 16 + 4 * c + 0], hv.x, a2);
      a2 = dot4i8(w[2 * 16 + 4 * c + 1], hv.y, a2);
      a2 = dot4i8(w[2 * 16 + 4 * c + 2], hv.z, a2);
      a2 = dot4i8(w[2 * 16 + 4 * c + 3], hv.w, a2);
      a3 = dot4i8(w[3 * 16 + 4 * c + 0], hv.x, a3);
      a3 = dot4i8(w[3 * 16 + 4 * c + 1], hv.y, a3);
      a3 = dot4i8(w[3 * 16 + 4 * c + 2], hv.z, a3);
      a3 = dot4i8(w[3 * 16 + 4 * c + 3], hv.w, a3);
      a4 = dot4i8(w[4 * 16 + 4 * c + 0], hv.x, a4);
      a4 = dot4i8(w[4 * 16 + 4 * c + 1], hv.y, a4);
      a4 = dot4i8(w[4 * 16 + 4 * c + 2], hv.z, a4);
      a4 = dot4i8(w[4 * 16 + 4 * c + 3], hv.w, a4);
      a5 = dot4i8(w[5 * 16 + 4 * c + 0], hv.x, a5);
      a5 = dot4i8(w[5 * 16 + 4 * c + 1], hv.y, a5);
      a5 = dot4i8(w[5 * 16 + 4 * c + 2], hv.z, a5);
      a5 = dot4i8(w[5 * 16 + 4 * c + 3], hv.w, a5);
      a6 = dot4i8(w[6 * 16 + 4 * c + 0], hv.x, a6);
      a6 = dot4i8(w[6 * 16 + 4 * c + 1], hv.y, a6);
      a6 = dot4i8(w[6 * 16 + 4 * c + 2], hv.z, a6);
      a6 = dot4i8(w[6 * 16 + 4 * c + 3], hv.w, a6);
      a7 = dot4i8(w[7 * 16 + 4 * c + 0], hv.x, a7);
      a7 = dot4i8(w[7 * 16 + 4 * c + 1], hv.y, a7);
      a7 = dot4i8(w[7 * 16 + 4 * c + 2], hv.z, a7);
      a7 = dot4i8(w[7 * 16 + 4 * c + 3], hv.w, a7);
    }
    // 7-exchange tree (own row ends in slot 0)
    const int q0 = a0 + dpp_xor1(a1);
    const int q1 = a2 + dpp_xor1(a3);
    const int q2 = a4 + dpp_xor1(a5);
    const int q3 = a6 + dpp_xor1(a7);
    const int r0 = q0 + dpp_xor2(q1);
    const int r1 = q2 + dpp_xor2(q3);
    const int res = r0 + swz_xor4(r1);

    // sigmoid via exp2 + single-inst rcp: e = 2^(afac*res + xpw) == e^{-z}
    const float e = exp2f((float)res * afac + xpw);
    const float s = fast_rcp(1.0f + e);
    h = h * (1.0f - ALPHA_F) + s * ALPHA_F;

    // i8 mirror write (single byte) BEFORE barrier
    hq[cur ^ 1][j + 16 * (j >> 6)] = (unsigned char)(__float2int_rn(h * 127.f));
    __syncthreads();

    *outp = h;  // after barrier: issues in the shadow of next step's dots
    cur ^= 1;
    xpp += BH;
    outp += BH;
  }

  if (t0 + ct == T_STEPS) {
    out[(size_t)T_STEPS * BATCH * HDIM + (size_t)b * HDIM + j] = h;
  }
}

// ---------------------------------------------------------------------------
extern "C" void kernel_launch(void* const* d_in, const int* in_sizes, int n_in,
                              void* d_out, int out_size, void* d_ws, size_t ws_size,
                              hipStream_t stream) {
  const float* x   = (const float*)d_in[0];
  const float* Win = (const float*)d_in[1];
  const float* Wh  = (const float*)d_in[2];
  const float* h0  = (const float*)d_in[3];
  float* out = (float*)d_out;
  float* xp  = (float*)d_ws;

  const size_t step_bytes = (size_t)BATCH * HDIM * sizeof(float);  // 128 KB
  int ct_max = (int)(ws_size / step_bytes);
  if (ct_max < 1) ct_max = 1;
  if (ct_max > T_STEPS) ct_max = T_STEPS;

  for (int t0 = 0; t0 < T_STEPS; t0 += ct_max) {
    const int ct = (T_STEPS - t0 < ct_max) ? (T_STEPS - t0) : ct_max;
    const int rows = ct * BATCH;
    const int mtiles = rows >> 4;
    const int gx = (mtiles < 1024) ? mtiles : 1024;
    hipLaunchKernelGGL(ctrnn_proj_mfma, dim3(gx, 2), dim3(256), 0, stream,
                       x + (size_t)t0 * BATCH * IDIM, Win, xp, rows);
    hipLaunchKernelGGL(ctrnn_scan, dim3(BATCH), dim3(512), 0, stream,
                       xp, Wh, h0, out, t0, ct);
  }
}